// Round 4
// baseline (145.263 us; speedup 1.0000x reference)
//
#include <hip/hip_runtime.h>

static constexpr int NN  = 100000;
static constexpr int NE  = 2400000;
static constexpr int BSH = 7;            // bucket shift
static constexpr int BSZ = 128;          // nodes per bucket
static constexpr int NB  = (NN + BSZ - 1) / BSZ;   // 782 buckets
static constexpr int NBP = 1024;         // padded bucket count (for scans)
static constexpr int NPB = 256;          // partition blocks
static constexpr int SEG = NE / NPB;     // 9375 edges per partition block
static_assert(NPB * SEG == NE, "exact segmentation");
static_assert(NB <= NBP, "bucket padding");
static_assert(NN % 16 == 0, "16-lane-per-node kernels assume NN % 16 == 0");

// ---- partition phase: counting sort of edges by dst bucket ----

__global__ __launch_bounds__(256) void khist(const int* __restrict__ dst,
                                             unsigned* __restrict__ H) {
    __shared__ unsigned h[NBP];
    int b = blockIdx.x;
    for (int t = threadIdx.x; t < NBP; t += 256) h[t] = 0;
    __syncthreads();
    int base = b * SEG;
    for (int j = threadIdx.x; j < SEG; j += 256)
        atomicAdd(&h[(unsigned)dst[base + j] >> BSH], 1u);
    __syncthreads();
    for (int t = threadIdx.x; t < NBP; t += 256) H[b * NBP + t] = h[t];
}

// per-bucket exclusive scan over the 256 partition blocks; one block per bucket
__global__ __launch_bounds__(256) void kcolscan(const unsigned* __restrict__ H,
                                                unsigned* __restrict__ P,
                                                unsigned* __restrict__ Hsum) {
    __shared__ unsigned a[256], b2[256];
    int k = blockIdx.x, t = threadIdx.x;
    unsigned v = H[(size_t)t * NBP + k];
    a[t] = v;
    __syncthreads();
    unsigned* cur = a; unsigned* nxt = b2;
    for (int off = 1; off < 256; off <<= 1) {
        unsigned x = cur[t];
        if (t >= off) x += cur[t - off];
        nxt[t] = x;
        __syncthreads();
        unsigned* tmp = cur; cur = nxt; nxt = tmp;
    }
    unsigned incl = cur[t];
    P[(size_t)t * NBP + k] = incl - v;     // exclusive prefix over blocks
    if (t == 255) Hsum[k] = incl;          // bucket total
}

// exclusive scan of the 1024 bucket totals; single block
__global__ __launch_bounds__(1024) void kbscan(const unsigned* __restrict__ Hsum,
                                               unsigned* __restrict__ base) {
    __shared__ unsigned a[1024], b2[1024];
    int t = threadIdx.x;
    unsigned v = Hsum[t];
    a[t] = v;
    __syncthreads();
    unsigned* cur = a; unsigned* nxt = b2;
    for (int off = 1; off < 1024; off <<= 1) {
        unsigned x = cur[t];
        if (t >= off) x += cur[t - off];
        nxt[t] = x;
        __syncthreads();
        unsigned* tmp = cur; cur = nxt; nxt = tmp;
    }
    base[t] = cur[t] - v;                  // exclusive
}

__global__ __launch_bounds__(256) void kscatter(const int* __restrict__ src,
                                                const int* __restrict__ dst,
                                                const unsigned* __restrict__ P,
                                                const unsigned* __restrict__ base,
                                                unsigned* __restrict__ csr) {
    __shared__ unsigned cur[NBP];
    int b = blockIdx.x;
    for (int t = threadIdx.x; t < NBP; t += 256)
        cur[t] = base[t] + P[(size_t)b * NBP + t];
    __syncthreads();
    int off = b * SEG;
    for (int j = threadIdx.x; j < SEG; j += 256) {
        int d = dst[off + j], s = src[off + j];
        unsigned pos = atomicAdd(&cur[(unsigned)d >> BSH], 1u);
        csr[pos] = ((unsigned)s << BSH) | (unsigned)(d & (BSZ - 1));
    }
}

// ---- second pass: node-sorted CSR within each bucket + rowptr + dis + y1 ----
__global__ __launch_bounds__(256) void kcsr(const unsigned* __restrict__ csr,
                                            const unsigned* __restrict__ basep,
                                            const unsigned* __restrict__ Hsum,
                                            const float* __restrict__ x,
                                            unsigned* __restrict__ csr2,
                                            unsigned* __restrict__ rowptr,
                                            float* __restrict__ dis,
                                            float* __restrict__ y1) {
    __shared__ int cnt[BSZ];
    __shared__ int sa[BSZ], sb[BSZ];
    __shared__ unsigned cur[BSZ];
    int k = blockIdx.x, t = threadIdx.x;
    if (t < BSZ) cnt[t] = 0;
    __syncthreads();
    unsigned s0 = basep[k], n = Hsum[k];
    for (unsigned j = t; j < n; j += 256)
        atomicAdd(&cnt[csr[s0 + j] & (BSZ - 1)], 1);
    __syncthreads();
    if (t < BSZ) sa[t] = cnt[t];
    __syncthreads();
    int* c = sa; int* xs = sb;
    for (int o = 1; o < BSZ; o <<= 1) {
        if (t < BSZ) { int v = c[t]; if (t >= o) v += c[t - o]; xs[t] = v; }
        __syncthreads();
        int* tmp = c; c = xs; xs = tmp;
    }
    int node = k * BSZ + t;
    if (t < BSZ) {
        int excl = c[t] - cnt[t];
        cur[t] = (unsigned)excl;
        if (node < NN) {
            rowptr[node] = s0 + excl;
            float d = rsqrtf((float)(cnt[t] + 1));
            dis[node] = d;
            y1[node] = d * x[node];
        }
    }
    if (k == 0 && t == 0) rowptr[NN] = NE;
    __syncthreads();
    for (unsigned j = t; j < n; j += 256) {
        unsigned cc = csr[s0 + j];
        unsigned pos = atomicAdd(&cur[cc & (BSZ - 1)], 1u);
        csr2[s0 + pos] = cc >> BSH;   // src node id, grouped by dst node
    }
}

// layer-1 aggregate (16 lanes/node) fused with 1->32->16 dense:
// a = dis*(sum y1[src] + y1[node]); lane g emits y2[node*16+g] = dis * (relu(a*W1+b1) @ W2)[g]
__global__ __launch_bounds__(256) void kagg1lin(const unsigned* __restrict__ srcs,
                                                const unsigned* __restrict__ rowptr,
                                                const float* __restrict__ y1,
                                                const float* __restrict__ dis,
                                                const float* __restrict__ W1,
                                                const float* __restrict__ b1,
                                                const float* __restrict__ W2,
                                                float* __restrict__ y2) {
    __shared__ float sW1[32], sb1[32], sW2[512];
    int t = threadIdx.x;
    if (t < 32) { sW1[t] = W1[t]; sb1[t] = b1[t]; }
    for (int i = t; i < 512; i += 256) sW2[i] = W2[i];
    __syncthreads();
    int node = blockIdx.x * 16 + (t >> 4);
    int g = t & 15;
    unsigned r0 = rowptr[node], r1 = rowptr[node + 1];
    float sum = 0.f;
    for (unsigned j = r0 + g; j < r1; j += 16) sum += y1[srcs[j]];
    sum += __shfl_xor(sum, 1, 16);
    sum += __shfl_xor(sum, 2, 16);
    sum += __shfl_xor(sum, 4, 16);
    sum += __shfl_xor(sum, 8, 16);          // all 16 lanes hold the total
    float d = dis[node];
    float a = d * (sum + y1[node]);
    float acc = 0.f;
#pragma unroll
    for (int f = 0; f < 32; ++f) {
        float h = fmaxf(a * sW1[f] + sb1[f], 0.f);
        acc += h * sW2[f * 16 + g];
    }
    y2[(size_t)node * 16 + g] = d * acc;
}

// 16-wide gather aggregate fused with layer-3 linear. Lane g owns feature g.
// One coalesced index load covers 16 edges; shfl broadcasts drive 16
// independent coalesced 64B row-gathers (high MLP, no redundant VMEM).
__global__ __launch_bounds__(256) void kagg16g(const unsigned* __restrict__ srcs,
                                               const unsigned* __restrict__ rowptr,
                                               const float* __restrict__ y2,
                                               const float* __restrict__ dis,
                                               const float* __restrict__ b2,
                                               const float* __restrict__ W3,
                                               float* __restrict__ y3) {
    int t = threadIdx.x;
    int node = blockIdx.x * 16 + (t >> 4);
    int g = t & 15;
    unsigned r0 = rowptr[node], r1 = rowptr[node + 1];
    unsigned cnt = r1 - r0;
    float sum = 0.f;
    for (unsigned kk = 0; kk < cnt; kk += 16) {
        unsigned idx = 0u;
        if (kk + g < cnt) idx = srcs[r0 + kk + g];
        unsigned rem = cnt - kk;             // uniform within the 16-lane group
#pragma unroll
        for (int e = 0; e < 16; ++e) {
            if ((unsigned)e < rem) {
                unsigned s = __shfl(idx, e, 16);
                sum += y2[(size_t)s * 16 + g];
            }
        }
    }
    float d = dis[node];
    float a2 = d * (sum + y2[(size_t)node * 16 + g]) + b2[g];
    float hg = fmaxf(a2, 0.f) * W3[g];
    hg += __shfl_xor(hg, 1, 16);
    hg += __shfl_xor(hg, 2, 16);
    hg += __shfl_xor(hg, 4, 16);
    hg += __shfl_xor(hg, 8, 16);
    if (g == 0) y3[node] = d * hg;
}

// scalar gather aggregate: 16 lanes per node
__global__ __launch_bounds__(256) void kaggsg(const unsigned* __restrict__ srcs,
                                              const unsigned* __restrict__ rowptr,
                                              const float* __restrict__ y,
                                              const float* __restrict__ dis,
                                              float* __restrict__ out,
                                              const float* __restrict__ bias) {
    int t = threadIdx.x;
    int node = blockIdx.x * 16 + (t >> 4);
    int g = t & 15;
    unsigned r0 = rowptr[node], r1 = rowptr[node + 1];
    float sum = 0.f;
    for (unsigned j = r0 + g; j < r1; j += 16) sum += y[srcs[j]];
    sum += __shfl_xor(sum, 1, 16);
    sum += __shfl_xor(sum, 2, 16);
    sum += __shfl_xor(sum, 4, 16);
    sum += __shfl_xor(sum, 8, 16);
    if (g == 0) {
        float d = dis[node];
        out[node] = d * (sum + y[node]) + (bias ? bias[0] : 0.f);
    }
}

extern "C" void kernel_launch(void* const* d_in, const int* in_sizes, int n_in,
                              void* d_out, int out_size, void* d_ws, size_t ws_size,
                              hipStream_t stream) {
    const float* x  = (const float*)d_in[0];
    const int*   ei = (const int*)d_in[1];
    const int* src = ei;
    const int* dst = ei + NE;
    const float* W1 = (const float*)d_in[2];
    const float* b1 = (const float*)d_in[3];
    const float* W2 = (const float*)d_in[4];
    const float* b2 = (const float*)d_in[5];
    const float* W3 = (const float*)d_in[6];
    const float* b3 = (const float*)d_in[7];
    float* out = (float*)d_out;

    auto align256 = [](size_t v) { return (v + 255) & ~(size_t)255; };
    char* w = (char*)d_ws;
    auto carve = [&](size_t bytes) { char* p = w; w += align256(bytes); return p; };

    // region A: bucket-sorted csr (dead after kcsr) -> reused as y2
    char* regA = carve((size_t)NE * 4);                       // 9.6 MB
    unsigned* csr = (unsigned*)regA;
    float*    y2  = (float*)regA;
    // region B: node-sorted csr2; H,P live here only during partition
    char* regB = carve((size_t)NE * 4);                       // 9.6 MB
    unsigned* csr2 = (unsigned*)regB;
    unsigned* H    = (unsigned*)regB;
    unsigned* P    = (unsigned*)(regB + (size_t)NPB * NBP * 4);
    unsigned* Hsum   = (unsigned*)carve((size_t)NBP * 4);
    unsigned* basep  = (unsigned*)carve((size_t)NBP * 4);
    unsigned* rowptr = (unsigned*)carve((size_t)(NN + 1) * 4);
    float*    dis    = (float*)   carve((size_t)NN * 4);
    float*    y1     = (float*)   carve((size_t)NN * 4);
    float*    y3     = (float*)   carve((size_t)NN * 4);

    dim3 B(256);

    // build bucket-sorted edge list, then node-sorted CSR (+rowptr, dis, y1)
    khist   <<<NPB, B, 0, stream>>>(dst, H);
    kcolscan<<<NBP, B, 0, stream>>>(H, P, Hsum);
    kbscan  <<<1, dim3(1024), 0, stream>>>(Hsum, basep);
    kscatter<<<NPB, B, 0, stream>>>(src, dst, P, basep, csr);
    kcsr    <<<NB,  B, 0, stream>>>(csr, basep, Hsum, x, csr2, rowptr, dis, y1);

    // layer 1 aggregate + dense 1->32->16 -> y2 = dis*h2pre
    kagg1lin<<<NN / 16, B, 0, stream>>>(csr2, rowptr, y1, dis, W1, b1, W2, y2);

    // layer 2 aggregate (16-wide) fused with layer-3 linear -> y3
    kagg16g <<<NN / 16, B, 0, stream>>>(csr2, rowptr, y2, dis, b2, W3, y3);

    // layer 3 aggregate (scalar) -> out
    kaggsg  <<<NN / 16, B, 0, stream>>>(csr2, rowptr, y3, dis, out, b3);
}

// Round 5
// 125.340 us; speedup vs baseline: 1.1589x; 1.1589x over previous
//
#include <hip/hip_runtime.h>

static constexpr int NN  = 100000;
static constexpr int NE  = 2400000;
static constexpr int BSH = 7;            // bucket shift
static constexpr int BSZ = 128;          // nodes per bucket
static constexpr int NB  = (NN + BSZ - 1) / BSZ;   // 782 buckets
static constexpr int NBP = 1024;         // padded bucket count (for scans)
static constexpr int NPB = 256;          // partition blocks
static constexpr int SEG = NE / NPB;     // 9375 edges per partition block
static_assert(NPB * SEG == NE, "exact segmentation");
static_assert(NB <= NBP, "bucket padding");
static_assert(NN % 16 == 0, "16-lane-per-node kernels assume NN % 16 == 0");

// ---- partition phase: counting sort of edges by dst bucket ----

__global__ __launch_bounds__(256) void khist(const int* __restrict__ dst,
                                             unsigned* __restrict__ H) {
    __shared__ unsigned h[NBP];
    int b = blockIdx.x;
    for (int t = threadIdx.x; t < NBP; t += 256) h[t] = 0;
    __syncthreads();
    int base = b * SEG;
    for (int j = threadIdx.x; j < SEG; j += 256)
        atomicAdd(&h[(unsigned)dst[base + j] >> BSH], 1u);
    __syncthreads();
    for (int t = threadIdx.x; t < NBP; t += 256) H[b * NBP + t] = h[t];
}

// per-bucket exclusive scan over the 256 partition blocks; one block per bucket
__global__ __launch_bounds__(256) void kcolscan(const unsigned* __restrict__ H,
                                                unsigned* __restrict__ P,
                                                unsigned* __restrict__ Hsum) {
    __shared__ unsigned a[256], b2[256];
    int k = blockIdx.x, t = threadIdx.x;
    unsigned v = H[(size_t)t * NBP + k];
    a[t] = v;
    __syncthreads();
    unsigned* cur = a; unsigned* nxt = b2;
    for (int off = 1; off < 256; off <<= 1) {
        unsigned x = cur[t];
        if (t >= off) x += cur[t - off];
        nxt[t] = x;
        __syncthreads();
        unsigned* tmp = cur; cur = nxt; nxt = tmp;
    }
    unsigned incl = cur[t];
    P[(size_t)t * NBP + k] = incl - v;     // exclusive prefix over blocks
    if (t == 255) Hsum[k] = incl;          // bucket total
}

// exclusive scan of the 1024 bucket totals; single block
__global__ __launch_bounds__(1024) void kbscan(const unsigned* __restrict__ Hsum,
                                               unsigned* __restrict__ base) {
    __shared__ unsigned a[1024], b2[1024];
    int t = threadIdx.x;
    unsigned v = Hsum[t];
    a[t] = v;
    __syncthreads();
    unsigned* cur = a; unsigned* nxt = b2;
    for (int off = 1; off < 1024; off <<= 1) {
        unsigned x = cur[t];
        if (t >= off) x += cur[t - off];
        nxt[t] = x;
        __syncthreads();
        unsigned* tmp = cur; cur = nxt; nxt = tmp;
    }
    base[t] = cur[t] - v;                  // exclusive
}

__global__ __launch_bounds__(256) void kscatter(const int* __restrict__ src,
                                                const int* __restrict__ dst,
                                                const unsigned* __restrict__ P,
                                                const unsigned* __restrict__ base,
                                                unsigned* __restrict__ csr) {
    __shared__ unsigned cur[NBP];
    int b = blockIdx.x;
    for (int t = threadIdx.x; t < NBP; t += 256)
        cur[t] = base[t] + P[(size_t)b * NBP + t];
    __syncthreads();
    int off = b * SEG;
    for (int j = threadIdx.x; j < SEG; j += 256) {
        int d = dst[off + j], s = src[off + j];
        unsigned pos = atomicAdd(&cur[(unsigned)d >> BSH], 1u);
        csr[pos] = ((unsigned)s << BSH) | (unsigned)(d & (BSZ - 1));
    }
}

// ---- second pass: node-sorted CSR within each bucket + rowptr + dis + y1 ----
__global__ __launch_bounds__(256) void kcsr(const unsigned* __restrict__ csr,
                                            const unsigned* __restrict__ basep,
                                            const unsigned* __restrict__ Hsum,
                                            const float* __restrict__ x,
                                            unsigned* __restrict__ csr2,
                                            unsigned* __restrict__ rowptr,
                                            float* __restrict__ dis,
                                            float* __restrict__ y1) {
    __shared__ int cnt[BSZ];
    __shared__ int sa[BSZ], sb[BSZ];
    __shared__ unsigned cur[BSZ];
    int k = blockIdx.x, t = threadIdx.x;
    if (t < BSZ) cnt[t] = 0;
    __syncthreads();
    unsigned s0 = basep[k], n = Hsum[k];
    for (unsigned j = t; j < n; j += 256)
        atomicAdd(&cnt[csr[s0 + j] & (BSZ - 1)], 1);
    __syncthreads();
    if (t < BSZ) sa[t] = cnt[t];
    __syncthreads();
    int* c = sa; int* xs = sb;
    for (int o = 1; o < BSZ; o <<= 1) {
        if (t < BSZ) { int v = c[t]; if (t >= o) v += c[t - o]; xs[t] = v; }
        __syncthreads();
        int* tmp = c; c = xs; xs = tmp;
    }
    int node = k * BSZ + t;
    if (t < BSZ) {
        int excl = c[t] - cnt[t];
        cur[t] = (unsigned)excl;
        if (node < NN) {
            rowptr[node] = s0 + excl;
            float d = rsqrtf((float)(cnt[t] + 1));
            dis[node] = d;
            y1[node] = d * x[node];
        }
    }
    if (k == 0 && t == 0) rowptr[NN] = NE;
    __syncthreads();
    for (unsigned j = t; j < n; j += 256) {
        unsigned cc = csr[s0 + j];
        unsigned pos = atomicAdd(&cur[cc & (BSZ - 1)], 1u);
        csr2[s0 + pos] = cc >> BSH;   // src node id, grouped by dst node
    }
}

// layer-1 aggregate (16 lanes/node, stride-16, 2 accumulators) fused with
// 1->32->16 dense: lane g emits y2[node*16+g]
__global__ __launch_bounds__(256) void kagg1lin(const unsigned* __restrict__ srcs,
                                                const unsigned* __restrict__ rowptr,
                                                const float* __restrict__ y1,
                                                const float* __restrict__ dis,
                                                const float* __restrict__ W1,
                                                const float* __restrict__ b1,
                                                const float* __restrict__ W2,
                                                float* __restrict__ y2) {
    __shared__ float sW1[32], sb1[32], sW2[512];
    int t = threadIdx.x;
    if (t < 32) { sW1[t] = W1[t]; sb1[t] = b1[t]; }
    for (int i = t; i < 512; i += 256) sW2[i] = W2[i];
    __syncthreads();
    int node = blockIdx.x * 16 + (t >> 4);
    int g = t & 15;
    unsigned r0 = rowptr[node], r1 = rowptr[node + 1];
    float s0 = 0.f, s1 = 0.f;
    unsigned j = r0 + g;
    for (; j + 16 < r1; j += 32) {
        unsigned i0 = srcs[j], i1 = srcs[j + 16];
        float v0 = y1[i0], v1 = y1[i1];
        s0 += v0; s1 += v1;
    }
    if (j < r1) s0 += y1[srcs[j]];
    float sum = s0 + s1;
    sum += __shfl_xor(sum, 1, 16);
    sum += __shfl_xor(sum, 2, 16);
    sum += __shfl_xor(sum, 4, 16);
    sum += __shfl_xor(sum, 8, 16);          // all 16 lanes hold the total
    float d = dis[node];
    float a = d * (sum + y1[node]);
    float acc = 0.f;
#pragma unroll
    for (int f = 0; f < 32; ++f) {
        float h = fmaxf(a * sW1[f] + sb1[f], 0.f);
        acc += h * sW2[f * 16 + g];
    }
    y2[(size_t)node * 16 + g] = d * acc;
}

// 16-wide gather aggregate fused with layer-3 linear. Lane g owns feature g,
// iterates over ALL edges of its node. Unroll 8 with 4 independent
// accumulators -> 8 gathers in flight per node-group (MLP is the bottleneck).
__global__ __launch_bounds__(256) void kagg16g(const unsigned* __restrict__ srcs,
                                               const unsigned* __restrict__ rowptr,
                                               const float* __restrict__ y2,
                                               const float* __restrict__ dis,
                                               const float* __restrict__ b2,
                                               const float* __restrict__ W3,
                                               float* __restrict__ y3) {
    int t = threadIdx.x;
    int node = blockIdx.x * 16 + (t >> 4);
    int g = t & 15;
    unsigned r0 = rowptr[node], r1 = rowptr[node + 1];
    const float* yg = y2 + g;
    float s0 = 0.f, s1 = 0.f, s2 = 0.f, s3 = 0.f;
    unsigned j = r0;
    for (; j + 8 <= r1; j += 8) {
        unsigned i0 = srcs[j + 0], i1 = srcs[j + 1], i2 = srcs[j + 2], i3 = srcs[j + 3];
        unsigned i4 = srcs[j + 4], i5 = srcs[j + 5], i6 = srcs[j + 6], i7 = srcs[j + 7];
        float v0 = yg[(size_t)i0 * 16], v1 = yg[(size_t)i1 * 16];
        float v2 = yg[(size_t)i2 * 16], v3 = yg[(size_t)i3 * 16];
        float v4 = yg[(size_t)i4 * 16], v5 = yg[(size_t)i5 * 16];
        float v6 = yg[(size_t)i6 * 16], v7 = yg[(size_t)i7 * 16];
        s0 += v0; s1 += v1; s2 += v2; s3 += v3;
        s0 += v4; s1 += v5; s2 += v6; s3 += v7;
    }
    for (; j + 2 <= r1; j += 2) {
        unsigned i0 = srcs[j], i1 = srcs[j + 1];
        float v0 = yg[(size_t)i0 * 16], v1 = yg[(size_t)i1 * 16];
        s0 += v0; s1 += v1;
    }
    if (j < r1) s2 += yg[(size_t)srcs[j] * 16];
    float sum = (s0 + s1) + (s2 + s3);
    float d = dis[node];
    float a2 = d * (sum + y2[(size_t)node * 16 + g]) + b2[g];
    float hg = fmaxf(a2, 0.f) * W3[g];
    hg += __shfl_xor(hg, 1, 16);
    hg += __shfl_xor(hg, 2, 16);
    hg += __shfl_xor(hg, 4, 16);
    hg += __shfl_xor(hg, 8, 16);
    if (g == 0) y3[node] = d * hg;
}

// scalar gather aggregate: 16 lanes per node, stride-16, 2 accumulators
__global__ __launch_bounds__(256) void kaggsg(const unsigned* __restrict__ srcs,
                                              const unsigned* __restrict__ rowptr,
                                              const float* __restrict__ y,
                                              const float* __restrict__ dis,
                                              float* __restrict__ out,
                                              const float* __restrict__ bias) {
    int t = threadIdx.x;
    int node = blockIdx.x * 16 + (t >> 4);
    int g = t & 15;
    unsigned r0 = rowptr[node], r1 = rowptr[node + 1];
    float s0 = 0.f, s1 = 0.f;
    unsigned j = r0 + g;
    for (; j + 16 < r1; j += 32) {
        unsigned i0 = srcs[j], i1 = srcs[j + 16];
        float v0 = y[i0], v1 = y[i1];
        s0 += v0; s1 += v1;
    }
    if (j < r1) s0 += y[srcs[j]];
    float sum = s0 + s1;
    sum += __shfl_xor(sum, 1, 16);
    sum += __shfl_xor(sum, 2, 16);
    sum += __shfl_xor(sum, 4, 16);
    sum += __shfl_xor(sum, 8, 16);
    if (g == 0) {
        float d = dis[node];
        out[node] = d * (sum + y[node]) + (bias ? bias[0] : 0.f);
    }
}

extern "C" void kernel_launch(void* const* d_in, const int* in_sizes, int n_in,
                              void* d_out, int out_size, void* d_ws, size_t ws_size,
                              hipStream_t stream) {
    const float* x  = (const float*)d_in[0];
    const int*   ei = (const int*)d_in[1];
    const int* src = ei;
    const int* dst = ei + NE;
    const float* W1 = (const float*)d_in[2];
    const float* b1 = (const float*)d_in[3];
    const float* W2 = (const float*)d_in[4];
    const float* b2 = (const float*)d_in[5];
    const float* W3 = (const float*)d_in[6];
    const float* b3 = (const float*)d_in[7];
    float* out = (float*)d_out;

    auto align256 = [](size_t v) { return (v + 255) & ~(size_t)255; };
    char* w = (char*)d_ws;
    auto carve = [&](size_t bytes) { char* p = w; w += align256(bytes); return p; };

    // region A: bucket-sorted csr (dead after kcsr) -> reused as y2
    char* regA = carve((size_t)NE * 4);                       // 9.6 MB
    unsigned* csr = (unsigned*)regA;
    float*    y2  = (float*)regA;
    // region B: node-sorted csr2; H,P live here only during partition
    char* regB = carve((size_t)NE * 4);                       // 9.6 MB
    unsigned* csr2 = (unsigned*)regB;
    unsigned* H    = (unsigned*)regB;
    unsigned* P    = (unsigned*)(regB + (size_t)NPB * NBP * 4);
    unsigned* Hsum   = (unsigned*)carve((size_t)NBP * 4);
    unsigned* basep  = (unsigned*)carve((size_t)NBP * 4);
    unsigned* rowptr = (unsigned*)carve((size_t)(NN + 1) * 4);
    float*    dis    = (float*)   carve((size_t)NN * 4);
    float*    y1     = (float*)   carve((size_t)NN * 4);
    float*    y3     = (float*)   carve((size_t)NN * 4);

    dim3 B(256);

    // build bucket-sorted edge list, then node-sorted CSR (+rowptr, dis, y1)
    khist   <<<NPB, B, 0, stream>>>(dst, H);
    kcolscan<<<NBP, B, 0, stream>>>(H, P, Hsum);
    kbscan  <<<1, dim3(1024), 0, stream>>>(Hsum, basep);
    kscatter<<<NPB, B, 0, stream>>>(src, dst, P, basep, csr);
    kcsr    <<<NB,  B, 0, stream>>>(csr, basep, Hsum, x, csr2, rowptr, dis, y1);

    // layer 1 aggregate + dense 1->32->16 -> y2 = dis*h2pre
    kagg1lin<<<NN / 16, B, 0, stream>>>(csr2, rowptr, y1, dis, W1, b1, W2, y2);

    // layer 2 aggregate (16-wide) fused with layer-3 linear -> y3
    kagg16g <<<NN / 16, B, 0, stream>>>(csr2, rowptr, y2, dis, b2, W3, y3);

    // layer 3 aggregate (scalar) -> out
    kaggsg  <<<NN / 16, B, 0, stream>>>(csr2, rowptr, y3, dis, out, b3);
}